// Round 1
// baseline (69.820 us; speedup 1.0000x reference)
//
#include <hip/hip_runtime.h>
#include <hip/hip_bf16.h>

// GraphAttention: B=8, N=2048, DIN=DOUT=64, tau=2.0, leaky 0.2, dense 0/1 A.
// Phase 1: Wx = x@W, e_src = Wx@a_src, e_dst = Wx@a_dst  (into d_ws)
// Phase 2: per-row masked softmax over e_src[n]+e_dst[m] (leaky), then
//          sparse alpha@Wx via ballot-driven gather (A is ~2% dense).

#define BQ 8
#define NQ 2048
#define DQ 64
#define TAUQ 2.0f
#define SLOPEQ 0.2f

__global__ __launch_bounds__(256) void gat_phase1(
    const float* __restrict__ x, const float* __restrict__ W,
    const float* __restrict__ a_src, const float* __restrict__ a_dst,
    float* __restrict__ Wx, float* __restrict__ esrc, float* __restrict__ edst)
{
    __shared__ float Wl[64 * 64];
    __shared__ float xl[4][64];
    const int t = threadIdx.x;
    for (int i = t; i < 64 * 64; i += 256) Wl[i] = W[i];
    const int wave = t >> 6, lane = t & 63;
    const int row = blockIdx.x * 4 + wave;          // row in [0, B*N)
    xl[wave][lane] = x[row * DQ + lane];
    __syncthreads();

    float acc = 0.f;
#pragma unroll
    for (int i = 0; i < 64; ++i)
        acc += xl[wave][i] * Wl[i * 64 + lane];     // xl broadcast, Wl 2-way (free)
    Wx[row * DQ + lane] = acc;

    float ps = acc * a_src[lane];
    float pd = acc * a_dst[lane];
#pragma unroll
    for (int o = 32; o > 0; o >>= 1) {
        ps += __shfl_xor(ps, o);
        pd += __shfl_xor(pd, o);
    }
    if (lane == 0) { esrc[row] = ps; edst[row] = pd; }
}

__global__ __launch_bounds__(256) void gat_phase2(
    const float* __restrict__ A, const float* __restrict__ Wx,
    const float* __restrict__ esrc, const float* __restrict__ edst,
    float* __restrict__ out)
{
    const int t = threadIdx.x;
    const int wave = t >> 6, lane = t & 63;
    const int row = blockIdx.x * 4 + wave;          // row in [0, B*N)
    const int b = row >> 11;                        // row / N
    const float* __restrict__ Arow = A + (size_t)row * NQ;
    const float* __restrict__ ed   = edst + b * NQ;
    const float  es = esrc[row];

    // ---- scan A row: lane holds 8 float4 = 32 e-values (m = k*256 + 4*lane + j)
    float4 ev[8];
    float mx = -INFINITY;
#pragma unroll
    for (int k = 0; k < 8; ++k) {
        const int m0 = k * 256 + 4 * lane;
        float4 a4 = *reinterpret_cast<const float4*>(Arow + m0);
        float4 d4 = *reinterpret_cast<const float4*>(ed + m0);
        float* ap = &a4.x;
        float* dp = &d4.x;
        float* ep = &ev[k].x;
#pragma unroll
        for (int j = 0; j < 4; ++j) {
            float e = es + dp[j];
            e = e > 0.f ? e : SLOPEQ * e;           // LeakyReLU(0.2)
            e = (ap[j] >= 1e-9f) ? e : -INFINITY;   // mask non-edges
            ep[j] = e;
            mx = fmaxf(mx, e);
        }
    }
#pragma unroll
    for (int o = 32; o > 0; o >>= 1) mx = fmaxf(mx, __shfl_xor(mx, o));

    // ---- p = exp((e - mx)/tau); masked (-inf) -> exp gives exactly 0
    const float invtau = 1.0f / TAUQ;
    float s = 0.f;
#pragma unroll
    for (int k = 0; k < 8; ++k) {
        float* ep = &ev[k].x;
#pragma unroll
        for (int j = 0; j < 4; ++j) {
            float p = __expf((ep[j] - mx) * invtau);
            ep[j] = p;
            s += p;
        }
    }
#pragma unroll
    for (int o = 32; o > 0; o >>= 1) s += __shfl_xor(s, o);
    const float inv = (s > 0.f) ? 1.0f / s : 0.f;   // empty row -> 0 (nan_to_num)

    // ---- sparse accumulate: out[row][lane] = sum_m alpha[m] * Wx[b,m,lane]
    const float* __restrict__ Wxb = Wx + (size_t)b * NQ * DQ;
    float acc = 0.f;
#pragma unroll
    for (int k = 0; k < 8; ++k) {
        float* ep = &ev[k].x;
#pragma unroll
        for (int j = 0; j < 4; ++j) {
            unsigned long long mask = __ballot(ep[j] > 0.f);
            while (mask) {                          // wave-uniform loop
                const int l = __builtin_ctzll(mask);
                mask &= mask - 1;
                const int m = k * 256 + 4 * l + j;
                const float p = __shfl(ep[j], l);   // broadcast edge weight
                acc += p * Wxb[m * DQ + lane];      // coalesced 256B row read
            }
        }
    }
    out[(size_t)row * DQ + lane] = acc * inv;
}

extern "C" void kernel_launch(void* const* d_in, const int* in_sizes, int n_in,
                              void* d_out, int out_size, void* d_ws, size_t ws_size,
                              hipStream_t stream) {
    const float* x     = (const float*)d_in[0];
    const float* A     = (const float*)d_in[1];
    const float* W     = (const float*)d_in[2];
    const float* a_src = (const float*)d_in[3];
    const float* a_dst = (const float*)d_in[4];
    float* out = (float*)d_out;

    float* Wx   = (float*)d_ws;                       // B*N*64 floats = 4 MB
    float* esrc = Wx + (size_t)BQ * NQ * DQ;          // B*N floats
    float* edst = esrc + (size_t)BQ * NQ;             // B*N floats

    const int blocks = BQ * NQ / 4;                   // 4 rows (waves) per block
    gat_phase1<<<blocks, 256, 0, stream>>>(x, W, a_src, a_dst, Wx, esrc, edst);
    gat_phase2<<<blocks, 256, 0, stream>>>(A, Wx, esrc, edst, out);
}